// Round 1
// baseline (683.826 us; speedup 1.0000x reference)
//
#include <hip/hip_runtime.h>
#include <hip/hip_bf16.h>

#define B_ 8192
#define L_ 200

// ---------------- ws layout (floats) ----------------
// att      [B*16]
// net      [B*82]
// buf1     [B*512]
// buf2     [B*512]
// acc      [12*512]   (sums/sumsq for 6 reductions)
// norm_acc [1]
#define OFF_ATT   0
#define OFF_NET   (OFF_ATT + B_*16)
#define OFF_BUF1  (OFF_NET + B_*82)
#define OFF_BUF2  (OFF_BUF1 + B_*512)
#define OFF_ACC   (OFF_BUF2 + B_*512)
#define OFF_NORM  (OFF_ACC + 12*512)

__global__ __launch_bounds__(256) void init_ws(float* acc) {
    // zero 12*512 accumulators + 1 norm accumulator
    for (int i = threadIdx.x; i < 12*512 + 1; i += 256) acc[i] = 0.f;
}

// ---------------- attention ----------------
__global__ __launch_bounds__(256) void attn_k(
    const int* __restrict__ feedid, const int* __restrict__ seq_ids,
    const int* __restrict__ seq_len,
    const float* __restrict__ e_feed, const float* __restrict__ e_seq,
    const float* __restrict__ aW1, const float* __restrict__ ab1,
    const float* __restrict__ aW2, const float* __restrict__ ab2,
    const float* __restrict__ aW3, const float* __restrict__ ab3,
    float* __restrict__ att)
{
    __shared__ float sQ[16];
    __shared__ float sQt[64];
    __shared__ float sCk[16][64];
    __shared__ float sW2T[32][64];
    __shared__ float sW3[32];
    __shared__ float sB2[32];
    __shared__ float red[4][16];

    const int b = blockIdx.x;
    const int tid = threadIdx.x;

    if (tid < 16) sQ[tid] = e_feed[(size_t)feedid[b] * 16 + tid];
    __syncthreads();

    // Ck[i][j] = aW1[16+i][j] - aW1[32+i][j] + q[i]*aW1[48+i][j]
    #pragma unroll
    for (int r = 0; r < 4; ++r) {
        int idx = tid + 256 * r;        // 1024 entries
        int i = idx >> 6, j = idx & 63;
        sCk[i][j] = aW1[(16 + i) * 64 + j] - aW1[(32 + i) * 64 + j]
                  + sQ[i] * aW1[(48 + i) * 64 + j];
    }
    // qterm[j] = ab1[j] + sum_i q[i]*(aW1[i][j] + aW1[32+i][j])
    if (tid < 64) {
        float s = ab1[tid];
        #pragma unroll
        for (int i = 0; i < 16; ++i)
            s = fmaf(sQ[i], aW1[i * 64 + tid] + aW1[(32 + i) * 64 + tid], s);
        sQt[tid] = s;
    }
    // W2 transposed: sW2T[jj][kk] = aW2[kk][jj]
    #pragma unroll
    for (int r = 0; r < 8; ++r) {
        int idx = tid + 256 * r;        // 2048 entries
        int jj = idx >> 6, kk = idx & 63;
        sW2T[jj][kk] = aW2[kk * 32 + jj];
    }
    if (tid < 32) { sW3[tid] = aW3[tid]; sB2[tid] = ab2[tid]; }
    __syncthreads();

    float k[16];
    float w = 0.f;
    const int l = tid;
    if (l < L_) {
        int sid = seq_ids[(size_t)b * L_ + l];
        const float4* kp = (const float4*)(e_seq + (size_t)sid * 16);
        float4 k0 = kp[0], k1 = kp[1], k2 = kp[2], k3 = kp[3];
        k[0]=k0.x; k[1]=k0.y; k[2]=k0.z; k[3]=k0.w;
        k[4]=k1.x; k[5]=k1.y; k[6]=k1.z; k[7]=k1.w;
        k[8]=k2.x; k[9]=k2.y; k[10]=k2.z; k[11]=k2.w;
        k[12]=k3.x; k[13]=k3.y; k[14]=k3.z; k[15]=k3.w;

        float h1[64];
        #pragma unroll
        for (int j = 0; j < 64; ++j) h1[j] = sQt[j];
        #pragma unroll
        for (int i = 0; i < 16; ++i) {
            float kv = k[i];
            #pragma unroll
            for (int j = 0; j < 64; ++j) h1[j] = fmaf(kv, sCk[i][j], h1[j]);
        }
        #pragma unroll
        for (int j = 0; j < 64; ++j) h1[j] = fmaxf(h1[j], 0.f);

        float score = ab3[0];
        for (int jj = 0; jj < 32; ++jj) {
            float s = sB2[jj];
            #pragma unroll
            for (int kk = 0; kk < 64; ++kk) s = fmaf(h1[kk], sW2T[jj][kk], s);
            score = fmaf(fmaxf(s, 0.f), sW3[jj], score);
        }
        w = (l < seq_len[b]) ? score : 0.f;
    } else {
        #pragma unroll
        for (int i = 0; i < 16; ++i) k[i] = 0.f;
    }

    const int lane = tid & 63, wv = tid >> 6;
    #pragma unroll
    for (int i = 0; i < 16; ++i) {
        float v = w * k[i];
        v += __shfl_xor(v, 32, 64); v += __shfl_xor(v, 16, 64);
        v += __shfl_xor(v, 8, 64);  v += __shfl_xor(v, 4, 64);
        v += __shfl_xor(v, 2, 64);  v += __shfl_xor(v, 1, 64);
        if (lane == 0) red[wv][i] = v;
    }
    __syncthreads();
    if (tid < 16)
        att[(size_t)b * 16 + tid] = red[0][tid] + red[1][tid] + red[2][tid] + red[3][tid];
}

// ---------------- build net matrix + l2 norm ----------------
__global__ __launch_bounds__(256) void build_net(
    const float* __restrict__ dense,
    const int* __restrict__ userid, const int* __restrict__ device_,
    const int* __restrict__ authorid, const int* __restrict__ song,
    const int* __restrict__ singer, const int* __restrict__ tag,
    const int* __restrict__ feedid,
    const float* __restrict__ e_user, const float* __restrict__ e_dev,
    const float* __restrict__ e_auth, const float* __restrict__ e_song,
    const float* __restrict__ e_singer, const float* __restrict__ e_tag,
    const float* __restrict__ e_feed,
    const float* __restrict__ att, float* __restrict__ net,
    float* __restrict__ norm_acc)
{
    const int b = blockIdx.x * 256 + threadIdx.x;
    float row[82];
    const float* d = dense + (size_t)b * 16;
    #pragma unroll
    for (int i = 0; i < 16; ++i) row[i] = d[i];
    const float* eu = e_user + (size_t)userid[b] * 16;
    #pragma unroll
    for (int i = 0; i < 16; ++i) row[16 + i] = eu[i];
    const float* ed = e_dev + (size_t)device_[b] * 2;
    row[32] = ed[0]; row[33] = ed[1];
    const float* ea = e_auth + (size_t)authorid[b] * 4;
    #pragma unroll
    for (int i = 0; i < 4; ++i) row[34 + i] = ea[i];
    const float* es = e_song + (size_t)song[b] * 4;
    #pragma unroll
    for (int i = 0; i < 4; ++i) row[38 + i] = es[i];
    const float* eg = e_singer + (size_t)singer[b] * 4;
    #pragma unroll
    for (int i = 0; i < 4; ++i) row[42 + i] = eg[i];
    const float* et = e_tag + (size_t)tag[b] * 4;
    #pragma unroll
    for (int i = 0; i < 4; ++i) row[46 + i] = et[i];
    const float* ef = e_feed + (size_t)feedid[b] * 16;
    #pragma unroll
    for (int i = 0; i < 16; ++i) row[50 + i] = ef[i];
    const float* at = att + (size_t)b * 16;
    #pragma unroll
    for (int i = 0; i < 16; ++i) row[66 + i] = at[i];

    float sq = 0.f;
    #pragma unroll
    for (int i = 16; i < 82; ++i) sq = fmaf(row[i], row[i], sq);

    float* o = net + (size_t)b * 82;
    #pragma unroll
    for (int i = 0; i < 82; ++i) o[i] = row[i];

    float nrm = sqrtf(sq);
    nrm += __shfl_xor(nrm, 32, 64); nrm += __shfl_xor(nrm, 16, 64);
    nrm += __shfl_xor(nrm, 8, 64);  nrm += __shfl_xor(nrm, 4, 64);
    nrm += __shfl_xor(nrm, 2, 64);  nrm += __shfl_xor(nrm, 1, 64);
    if ((threadIdx.x & 63) == 0) atomicAdd(norm_acc, nrm);
}

// ---------------- f32 tiled GEMM + bias: C[M,N] = A[M,K] @ B[K,N] + bias ----------------
#define BM 64
#define BN 64
#define BK 16
__global__ __launch_bounds__(256) void gemm_bias(
    const float* __restrict__ A, const float* __restrict__ Bm,
    const float* __restrict__ bias, float* __restrict__ C,
    int M, int N, int K)
{
    __shared__ float As[BK][BM];
    __shared__ float Bs[BK][BN];
    const int bm = blockIdx.y * BM, bn = blockIdx.x * BN;
    const int tid = threadIdx.x;
    const int tx = tid & 15, ty = tid >> 4;
    float acc[4][4] = {{0.f}};

    for (int k0 = 0; k0 < K; k0 += BK) {
        {   // A tile: thread t -> row m = t>>2, 4 consecutive k
            int m = tid >> 2, kb = (tid & 3) * 4;
            const float* Ap = A + (size_t)(bm + m) * K + k0 + kb;
            #pragma unroll
            for (int j = 0; j < 4; ++j) {
                int kg = k0 + kb + j;
                As[kb + j][m] = (kg < K) ? Ap[j] : 0.f;
            }
        }
        {   // B tile: coalesced
            #pragma unroll
            for (int r = 0; r < 4; ++r) {
                int idx = tid + 256 * r;
                int kk = idx >> 6, n = idx & 63;
                int kg = k0 + kk;
                Bs[kk][n] = (kg < K) ? Bm[(size_t)kg * N + bn + n] : 0.f;
            }
        }
        __syncthreads();
        #pragma unroll
        for (int kk = 0; kk < BK; ++kk) {
            float a[4], bb[4];
            #pragma unroll
            for (int i = 0; i < 4; ++i) a[i] = As[kk][ty * 4 + i];
            #pragma unroll
            for (int i = 0; i < 4; ++i) bb[i] = Bs[kk][tx * 4 + i];
            #pragma unroll
            for (int i = 0; i < 4; ++i)
                #pragma unroll
                for (int j = 0; j < 4; ++j)
                    acc[i][j] = fmaf(a[i], bb[j], acc[i][j]);
        }
        __syncthreads();
    }
    #pragma unroll
    for (int i = 0; i < 4; ++i) {
        int m = bm + ty * 4 + i;
        #pragma unroll
        for (int j = 0; j < 4; ++j) {
            int n = bn + tx * 4 + j;
            C[(size_t)m * N + n] = acc[i][j] + bias[n];
        }
    }
}

// ---------------- column sum / sumsq ----------------
__global__ __launch_bounds__(256) void colreduce(
    const float* __restrict__ X, int M, int N, int chunk,
    float* __restrict__ sums, float* __restrict__ sqs)
{
    const int c = blockIdx.x * 256 + threadIdx.x;
    if (c >= N) return;
    const int r0 = blockIdx.y * chunk;
    const int r1 = min(M, r0 + chunk);
    float s = 0.f, q = 0.f;
    for (int r = r0; r < r1; ++r) {
        float v = X[(size_t)r * N + c];
        s += v; q = fmaf(v, v, q);
    }
    atomicAdd(&sums[c], s);
    atomicAdd(&sqs[c], q);
}

// ---------------- Dice elementwise ----------------
__global__ __launch_bounds__(256) void dice_ew(
    const float* __restrict__ X, float* __restrict__ D,
    const float* __restrict__ sums, const float* __restrict__ sqs,
    const float* __restrict__ alpha, int total, int Nmask, float invM)
{
    const int idx = blockIdx.x * 256 + threadIdx.x;
    if (idx >= total) return;
    const int c = idx & Nmask;
    const float m = sums[c] * invM;
    const float v = fmaf(-m, m, sqs[c] * invM);
    const float x = X[idx];
    const float xn = (x - m) * rsqrtf(v + 1e-5f);
    const float p = 1.f / (1.f + __expf(-xn));
    D[idx] = x * (p + alpha[c] * (1.f - p));
}

// ---------------- affine BN elementwise ----------------
__global__ __launch_bounds__(256) void bn_ew(
    const float* __restrict__ D, float* __restrict__ Y,
    const float* __restrict__ sums, const float* __restrict__ sqs,
    const float* __restrict__ g, const float* __restrict__ beta,
    int total, int Nmask, float invM)
{
    const int idx = blockIdx.x * 256 + threadIdx.x;
    if (idx >= total) return;
    const int c = idx & Nmask;
    const float m = sums[c] * invM;
    const float v = fmaf(-m, m, sqs[c] * invM);
    const float d = D[idx];
    Y[idx] = g[c] * (d - m) * rsqrtf(v + 1e-5f) + beta[c];
}

// ---------------- final: logit, prob, l2 ----------------
__global__ __launch_bounds__(256) void final_k(
    const float* __restrict__ Y, const float* __restrict__ Wout,
    const float* __restrict__ bout, const float* __restrict__ norm_acc,
    float* __restrict__ out)
{
    const int wv = threadIdx.x >> 6, lane = threadIdx.x & 63;
    const int b = blockIdx.x * 4 + wv;
    const float* y = Y + (size_t)b * 128;
    float s = fmaf(y[lane], Wout[lane], y[64 + lane] * Wout[64 + lane]);
    s += __shfl_xor(s, 32, 64); s += __shfl_xor(s, 16, 64);
    s += __shfl_xor(s, 8, 64);  s += __shfl_xor(s, 4, 64);
    s += __shfl_xor(s, 2, 64);  s += __shfl_xor(s, 1, 64);
    if (lane == 0) {
        float logit = s + bout[0];
        out[B_ + b] = logit;
        out[b] = 1.f / (1.f + __expf(-logit));
    }
    if (blockIdx.x == 0 && threadIdx.x == 0)
        out[2 * B_] = 0.2f * norm_acc[0] / (float)B_;
}

extern "C" void kernel_launch(void* const* d_in, const int* in_sizes, int n_in,
                              void* d_out, int out_size, void* d_ws, size_t ws_size,
                              hipStream_t stream)
{
    const float* dense    = (const float*)d_in[0];
    const int*   userid   = (const int*)d_in[1];
    const int*   device_  = (const int*)d_in[2];
    const int*   authorid = (const int*)d_in[3];
    const int*   song     = (const int*)d_in[4];
    const int*   singer   = (const int*)d_in[5];
    const int*   tag      = (const int*)d_in[6];
    const int*   feedid   = (const int*)d_in[7];
    const int*   seq_ids  = (const int*)d_in[8];
    const int*   seq_len  = (const int*)d_in[9];
    const float* e_user   = (const float*)d_in[10];
    const float* e_dev    = (const float*)d_in[11];
    const float* e_auth   = (const float*)d_in[12];
    const float* e_song   = (const float*)d_in[13];
    const float* e_singer = (const float*)d_in[14];
    const float* e_tag    = (const float*)d_in[15];
    const float* e_feed   = (const float*)d_in[16];
    const float* e_seq    = (const float*)d_in[17];
    const float* aW1 = (const float*)d_in[18];
    const float* ab1 = (const float*)d_in[19];
    const float* aW2 = (const float*)d_in[20];
    const float* ab2 = (const float*)d_in[21];
    const float* aW3 = (const float*)d_in[22];
    const float* ab3 = (const float*)d_in[23];
    const float* W0 = (const float*)d_in[24]; const float* b0 = (const float*)d_in[25];
    const float* al0 = (const float*)d_in[26]; const float* g0 = (const float*)d_in[27];
    const float* be0 = (const float*)d_in[28];
    const float* W1 = (const float*)d_in[29]; const float* b1 = (const float*)d_in[30];
    const float* al1 = (const float*)d_in[31]; const float* g1 = (const float*)d_in[32];
    const float* be1 = (const float*)d_in[33];
    const float* W2 = (const float*)d_in[34]; const float* b2 = (const float*)d_in[35];
    const float* al2 = (const float*)d_in[36]; const float* g2 = (const float*)d_in[37];
    const float* be2 = (const float*)d_in[38];
    const float* Wout = (const float*)d_in[39]; const float* bout = (const float*)d_in[40];

    float* ws   = (float*)d_ws;
    float* att  = ws + OFF_ATT;
    float* net  = ws + OFF_NET;
    float* buf1 = ws + OFF_BUF1;
    float* buf2 = ws + OFF_BUF2;
    float* acc  = ws + OFF_ACC;
    float* norm = ws + OFF_NORM;
    float* out  = (float*)d_out;

    // accumulator slots: layer i: sX = acc+(4i)*512, qX = +512, sD = +1024, qD = +1536
    float* sX0 = acc + 0*512;  float* qX0 = acc + 1*512;
    float* sD0 = acc + 2*512;  float* qD0 = acc + 3*512;
    float* sX1 = acc + 4*512;  float* qX1 = acc + 5*512;
    float* sD1 = acc + 6*512;  float* qD1 = acc + 7*512;
    float* sX2 = acc + 8*512;  float* qX2 = acc + 9*512;
    float* sD2 = acc + 10*512; float* qD2 = acc + 11*512;

    const float invB = 1.f / (float)B_;

    hipLaunchKernelGGL(init_ws, dim3(1), dim3(256), 0, stream, acc);

    hipLaunchKernelGGL(attn_k, dim3(B_), dim3(256), 0, stream,
                       feedid, seq_ids, seq_len, e_feed, e_seq,
                       aW1, ab1, aW2, ab2, aW3, ab3, att);

    hipLaunchKernelGGL(build_net, dim3(B_/256), dim3(256), 0, stream,
                       dense, userid, device_, authorid, song, singer, tag, feedid,
                       e_user, e_dev, e_auth, e_song, e_singer, e_tag, e_feed,
                       att, net, norm);

    // ---- layer 0: 82 -> 512 ----
    hipLaunchKernelGGL(gemm_bias, dim3(512/BN, B_/BM), dim3(256), 0, stream,
                       net, W0, b0, buf1, B_, 512, 82);
    hipLaunchKernelGGL(colreduce, dim3(2, B_/64), dim3(256), 0, stream,
                       buf1, B_, 512, 64, sX0, qX0);
    hipLaunchKernelGGL(dice_ew, dim3(B_*512/256), dim3(256), 0, stream,
                       buf1, buf2, sX0, qX0, al0, B_*512, 511, invB);
    hipLaunchKernelGGL(colreduce, dim3(2, B_/64), dim3(256), 0, stream,
                       buf2, B_, 512, 64, sD0, qD0);
    hipLaunchKernelGGL(bn_ew, dim3(B_*512/256), dim3(256), 0, stream,
                       buf2, buf1, sD0, qD0, g0, be0, B_*512, 511, invB);

    // ---- layer 1: 512 -> 256 ----
    hipLaunchKernelGGL(gemm_bias, dim3(256/BN, B_/BM), dim3(256), 0, stream,
                       buf1, W1, b1, buf2, B_, 256, 512);
    hipLaunchKernelGGL(colreduce, dim3(1, B_/64), dim3(256), 0, stream,
                       buf2, B_, 256, 64, sX1, qX1);
    hipLaunchKernelGGL(dice_ew, dim3(B_*256/256), dim3(256), 0, stream,
                       buf2, buf1, sX1, qX1, al1, B_*256, 255, invB);
    hipLaunchKernelGGL(colreduce, dim3(1, B_/64), dim3(256), 0, stream,
                       buf1, B_, 256, 64, sD1, qD1);
    hipLaunchKernelGGL(bn_ew, dim3(B_*256/256), dim3(256), 0, stream,
                       buf1, buf2, sD1, qD1, g1, be1, B_*256, 255, invB);

    // ---- layer 2: 256 -> 128 ----
    hipLaunchKernelGGL(gemm_bias, dim3(128/BN, B_/BM), dim3(256), 0, stream,
                       buf2, W2, b2, buf1, B_, 128, 256);
    hipLaunchKernelGGL(colreduce, dim3(1, B_/64), dim3(256), 0, stream,
                       buf1, B_, 128, 64, sX2, qX2);
    hipLaunchKernelGGL(dice_ew, dim3(B_*128/256), dim3(256), 0, stream,
                       buf1, buf2, sX2, qX2, al2, B_*128, 127, invB);
    hipLaunchKernelGGL(colreduce, dim3(1, B_/64), dim3(256), 0, stream,
                       buf2, B_, 128, 64, sD2, qD2);
    hipLaunchKernelGGL(bn_ew, dim3(B_*128/256), dim3(256), 0, stream,
                       buf2, buf1, sD2, qD2, g2, be2, B_*128, 127, invB);

    // ---- final ----
    hipLaunchKernelGGL(final_k, dim3(B_/4), dim3(256), 0, stream,
                       buf1, Wout, bout, norm, out);
}

// Round 2
// 486.573 us; speedup vs baseline: 1.4054x; 1.4054x over previous
//
#include <hip/hip_runtime.h>
#include <hip/hip_bf16.h>

#define B_ 8192
#define L_ 200

typedef __attribute__((ext_vector_type(4))) short s4v;
typedef __attribute__((ext_vector_type(8))) short s8v;
typedef __attribute__((ext_vector_type(16))) float f32x16;

__device__ __forceinline__ short f2bf(float f) {
    union { float f; unsigned u; } v; v.f = f;
    unsigned r = (v.u + 0x7fffu + ((v.u >> 16) & 1u)) >> 16;
    return (short)r;
}
__device__ __forceinline__ float bf2f(short s) {
    union { unsigned u; float f; } v; v.u = ((unsigned)(unsigned short)s) << 16;
    return v.f;
}

// ---------------- ws layout (floats) ----------------
#define OFF_ATT   0
#define OFF_NET   (OFF_ATT + B_*16)
#define OFF_BUF1  (OFF_NET + B_*82)
#define OFF_BUF2  (OFF_BUF1 + B_*512)
#define OFF_ACC   (OFF_BUF2 + B_*512)
#define OFF_NORM  (OFF_ACC + 12*512)

__global__ __launch_bounds__(256) void init_ws(float* acc) {
    for (int i = threadIdx.x; i < 12*512 + 1; i += 256) acc[i] = 0.f;
}

// ---------------- MFMA attention: one block per batch row ----------------
// layer1: h1[224,64] = K[224,16] @ Ck[16,64]   (7 Mtiles x 2 Ntiles, K=16)
// layer2: h2[224,32] = relu(h1)[224,64] @ W2[64,32]  (7 Mtiles x 4 Ksteps)
// score via in-register W3 dot + shfl reduce.
__global__ __launch_bounds__(256) void attn_k(
    const int* __restrict__ feedid, const int* __restrict__ seq_ids,
    const int* __restrict__ seq_len,
    const float* __restrict__ e_feed, const float* __restrict__ e_seq,
    const float* __restrict__ aW1, const float* __restrict__ ab1,
    const float* __restrict__ aW2, const float* __restrict__ ab2,
    const float* __restrict__ aW3, const float* __restrict__ ab3,
    float* __restrict__ att)
{
    __shared__ short KL[224*20];      // K bf16, row stride 20
    __shared__ short CkT[64*16];      // Ck transposed [j][i]
    __shared__ float qterm[64];
    __shared__ short W2T[32*72];      // W2 transposed [n][k], stride 72
    __shared__ float w3s[32];
    __shared__ float qS[16];
    __shared__ short h1[224*68];      // h1 bf16, row stride 68 (136B)
    __shared__ float wS[224];
    __shared__ float pS[16*16];

    const int b = blockIdx.x;
    const int t = threadIdx.x;

    if (t < 16) qS[t] = e_feed[(size_t)feedid[b] * 16 + t];
    __syncthreads();

    // stage K (gather, f32 -> bf16): 200 rows x 4 float4 chunks
    for (int idx = t; idx < 800; idx += 256) {
        int row = idx >> 2, p = idx & 3;
        int sid = seq_ids[(size_t)b * L_ + row];
        const float4 f4 = ((const float4*)(e_seq + (size_t)sid * 16))[p];
        s4v v; v[0]=f2bf(f4.x); v[1]=f2bf(f4.y); v[2]=f2bf(f4.z); v[3]=f2bf(f4.w);
        *(s4v*)&KL[row * 20 + p * 4] = v;
    }
    // zero-pad rows 200..223
    if (t < 96) {
        int row = 200 + (t >> 2), p = t & 3;
        s4v z = {0,0,0,0};
        *(s4v*)&KL[row * 20 + p * 4] = z;
    }
    // CkT[j][i] = bf16(aW1[16+i][j] - aW1[32+i][j] + q[i]*aW1[48+i][j])
    #pragma unroll
    for (int r = 0; r < 4; ++r) {
        int idx = t + 256 * r;
        int i = idx >> 6, j = idx & 63;
        float v = aW1[(16 + i) * 64 + j] - aW1[(32 + i) * 64 + j]
                + qS[i] * aW1[(48 + i) * 64 + j];
        CkT[j * 16 + i] = f2bf(v);
    }
    // qterm[j] = ab1[j] + sum_i q[i]*(aW1[i][j] + aW1[32+i][j])
    if (t < 64) {
        float s = ab1[t];
        #pragma unroll
        for (int i = 0; i < 16; ++i)
            s = fmaf(qS[i], aW1[i * 64 + t] + aW1[(32 + i) * 64 + t], s);
        qterm[t] = s;
    }
    // W2T[n][kk]
    #pragma unroll
    for (int r = 0; r < 8; ++r) {
        int idx = t + 256 * r;
        int kk = idx >> 5, n = idx & 31;
        W2T[n * 72 + kk] = f2bf(aW2[kk * 32 + n]);
    }
    if (t < 32) w3s[t] = aW3[t];
    __syncthreads();

    const int wave = t >> 6, half = (t >> 5) & 1, lane31 = t & 31;
    const float ab3v = ab3[0];
    const int len = seq_len[b];

    for (int m = wave; m < 7; m += 4) {
        // A fragment: K rows
        const int g = m * 32 + lane31;
        const int abase = g * 20 + half * 8;
        s4v lo = *(const s4v*)&KL[abase];
        s4v hi = *(const s4v*)&KL[abase + 4];
        s8v afrag;
        afrag[0]=lo[0]; afrag[1]=lo[1]; afrag[2]=lo[2]; afrag[3]=lo[3];
        afrag[4]=hi[0]; afrag[5]=hi[1]; afrag[6]=hi[2]; afrag[7]=hi[3];

        // layer 1: two N-tiles
        #pragma unroll
        for (int nt = 0; nt < 2; ++nt) {
            const s8v bfrag = *(const s8v*)&CkT[(nt * 32 + lane31) * 16 + half * 8];
            f32x16 acc;
            #pragma unroll
            for (int i = 0; i < 16; ++i) acc[i] = 0.f;
            acc = __builtin_amdgcn_mfma_f32_32x32x16_bf16(afrag, bfrag, acc, 0, 0, 0);
            const float qt = qterm[nt * 32 + lane31];
            #pragma unroll
            for (int r = 0; r < 16; ++r) {
                float v = fmaxf(acc[r] + qt, 0.f);
                int row = m * 32 + (r & 3) + 8 * (r >> 2) + 4 * half;
                h1[row * 68 + nt * 32 + lane31] = f2bf(v);
            }
        }

        // layer 2: 4 K-steps, N=32
        f32x16 acc2;
        #pragma unroll
        for (int i = 0; i < 16; ++i) acc2[i] = 0.f;
        const int hrow = m * 32 + lane31;
        #pragma unroll
        for (int ks = 0; ks < 4; ++ks) {
            const int kb = ks * 16 + half * 8;
            s4v l2 = *(const s4v*)&h1[hrow * 68 + kb];
            s4v h2 = *(const s4v*)&h1[hrow * 68 + kb + 4];
            s8v a2;
            a2[0]=l2[0]; a2[1]=l2[1]; a2[2]=l2[2]; a2[3]=l2[3];
            a2[4]=h2[0]; a2[5]=h2[1]; a2[6]=h2[2]; a2[7]=h2[3];
            const s8v b2 = *(const s8v*)&W2T[lane31 * 72 + kb];
            acc2 = __builtin_amdgcn_mfma_f32_32x32x16_bf16(a2, b2, acc2, 0, 0, 0);
        }

        // score: relu(h2) * W3, reduce across the 32-lane column group
        const float w3v = w3s[lane31];
        #pragma unroll
        for (int r = 0; r < 16; ++r) {
            float v = fmaxf(acc2[r], 0.f) * w3v;
            v += __shfl_xor(v, 1);  v += __shfl_xor(v, 2);
            v += __shfl_xor(v, 4);  v += __shfl_xor(v, 8);
            v += __shfl_xor(v, 16);
            if (lane31 == 0) {
                int row = m * 32 + (r & 3) + 8 * (r >> 2) + 4 * half;
                wS[row] = (row < len) ? (v + ab3v) : 0.f;
            }
        }
    }
    __syncthreads();

    // att_out[c] = sum_l w[l] * K[l][c]
    {
        const int c = t & 15, ch = t >> 4;
        const int r0 = ch * 14;
        float s = 0.f;
        #pragma unroll
        for (int i = 0; i < 14; ++i) {
            int r = r0 + i;
            s = fmaf(wS[r], bf2f(KL[r * 20 + c]), s);
        }
        pS[ch * 16 + c] = s;
    }
    __syncthreads();
    if (t < 16) {
        float s = 0.f;
        #pragma unroll
        for (int ch = 0; ch < 16; ++ch) s += pS[ch * 16 + t];
        att[(size_t)b * 16 + t] = s;
    }
}

// ---------------- build net matrix + l2 norm ----------------
__global__ __launch_bounds__(256) void build_net(
    const float* __restrict__ dense,
    const int* __restrict__ userid, const int* __restrict__ device_,
    const int* __restrict__ authorid, const int* __restrict__ song,
    const int* __restrict__ singer, const int* __restrict__ tag,
    const int* __restrict__ feedid,
    const float* __restrict__ e_user, const float* __restrict__ e_dev,
    const float* __restrict__ e_auth, const float* __restrict__ e_song,
    const float* __restrict__ e_singer, const float* __restrict__ e_tag,
    const float* __restrict__ e_feed,
    const float* __restrict__ att, float* __restrict__ net,
    float* __restrict__ norm_acc)
{
    const int b = blockIdx.x * 256 + threadIdx.x;
    float row[82];
    const float* d = dense + (size_t)b * 16;
    #pragma unroll
    for (int i = 0; i < 16; ++i) row[i] = d[i];
    const float* eu = e_user + (size_t)userid[b] * 16;
    #pragma unroll
    for (int i = 0; i < 16; ++i) row[16 + i] = eu[i];
    const float* ed = e_dev + (size_t)device_[b] * 2;
    row[32] = ed[0]; row[33] = ed[1];
    const float* ea = e_auth + (size_t)authorid[b] * 4;
    #pragma unroll
    for (int i = 0; i < 4; ++i) row[34 + i] = ea[i];
    const float* es = e_song + (size_t)song[b] * 4;
    #pragma unroll
    for (int i = 0; i < 4; ++i) row[38 + i] = es[i];
    const float* eg = e_singer + (size_t)singer[b] * 4;
    #pragma unroll
    for (int i = 0; i < 4; ++i) row[42 + i] = eg[i];
    const float* et = e_tag + (size_t)tag[b] * 4;
    #pragma unroll
    for (int i = 0; i < 4; ++i) row[46 + i] = et[i];
    const float* ef = e_feed + (size_t)feedid[b] * 16;
    #pragma unroll
    for (int i = 0; i < 16; ++i) row[50 + i] = ef[i];
    const float* at = att + (size_t)b * 16;
    #pragma unroll
    for (int i = 0; i < 16; ++i) row[66 + i] = at[i];

    float sq = 0.f;
    #pragma unroll
    for (int i = 16; i < 82; ++i) sq = fmaf(row[i], row[i], sq);

    float* o = net + (size_t)b * 82;
    #pragma unroll
    for (int i = 0; i < 82; ++i) o[i] = row[i];

    float nrm = sqrtf(sq);
    nrm += __shfl_xor(nrm, 32); nrm += __shfl_xor(nrm, 16);
    nrm += __shfl_xor(nrm, 8);  nrm += __shfl_xor(nrm, 4);
    nrm += __shfl_xor(nrm, 2);  nrm += __shfl_xor(nrm, 1);
    if ((threadIdx.x & 63) == 0) atomicAdd(norm_acc, nrm);
}

// ---------------- f32 GEMM + bias + optional BN-fold on A + output col stats ----------------
#define BM 64
#define BN 64
#define BK 16
__global__ __launch_bounds__(256) void gemm_bias_stats(
    const float* __restrict__ A, const float* __restrict__ Bm,
    const float* __restrict__ bias, float* __restrict__ C,
    int M, int N, int K,
    const float* __restrict__ sin_, const float* __restrict__ qin_,
    const float* __restrict__ gin_, const float* __restrict__ bein_,
    float* __restrict__ sout, float* __restrict__ qout, float invB)
{
    __shared__ float As[BK][BM];
    __shared__ float Bs[BK][BN];
    __shared__ float scl[512], sft[512];
    __shared__ float colS[BN], colQ[BN];

    const int bm = blockIdx.y * BM, bn = blockIdx.x * BN;
    const int tid = threadIdx.x;
    const int tx = tid & 15, ty = tid >> 4;

    if (tid < BN) { colS[tid] = 0.f; colQ[tid] = 0.f; }
    // precompute per-column scale/shift for the BN fold on A
    for (int c = tid; c < K; c += 256) {
        if (gin_) {
            float m = sin_[c] * invB;
            float v = fmaf(-m, m, qin_[c] * invB);
            float sc = gin_[c] * rsqrtf(v + 1e-5f);
            scl[c] = sc; sft[c] = bein_[c] - m * sc;
        } else { scl[c] = 1.f; sft[c] = 0.f; }
    }
    __syncthreads();

    float acc[4][4] = {{0.f}};
    for (int k0 = 0; k0 < K; k0 += BK) {
        {
            int m = tid >> 2, kb = (tid & 3) * 4;
            const float* Ap = A + (size_t)(bm + m) * K + k0 + kb;
            #pragma unroll
            for (int j = 0; j < 4; ++j) {
                int kg = k0 + kb + j;
                As[kb + j][m] = (kg < K) ? fmaf(Ap[j], scl[kg], sft[kg]) : 0.f;
            }
        }
        {
            #pragma unroll
            for (int r = 0; r < 4; ++r) {
                int idx = tid + 256 * r;
                int kk = idx >> 6, n = idx & 63;
                int kg = k0 + kk;
                Bs[kk][n] = (kg < K) ? Bm[(size_t)kg * N + bn + n] : 0.f;
            }
        }
        __syncthreads();
        #pragma unroll
        for (int kk = 0; kk < BK; ++kk) {
            float a[4], bb[4];
            #pragma unroll
            for (int i = 0; i < 4; ++i) a[i] = As[kk][ty * 4 + i];
            #pragma unroll
            for (int i = 0; i < 4; ++i) bb[i] = Bs[kk][tx * 4 + i];
            #pragma unroll
            for (int i = 0; i < 4; ++i)
                #pragma unroll
                for (int j = 0; j < 4; ++j)
                    acc[i][j] = fmaf(a[i], bb[j], acc[i][j]);
        }
        __syncthreads();
    }

    // epilogue: store + per-column stats (wave reduce over ty, LDS atomics, global atomics)
    #pragma unroll
    for (int j = 0; j < 4; ++j) {
        const int n = bn + tx * 4 + j;
        const float bv = bias[n];
        float s = 0.f, q = 0.f;
        #pragma unroll
        for (int i = 0; i < 4; ++i) {
            float x = acc[i][j] + bv;
            C[(size_t)(bm + ty * 4 + i) * N + n] = x;
            s += x; q = fmaf(x, x, q);
        }
        s += __shfl_xor(s, 16); s += __shfl_xor(s, 32);
        q += __shfl_xor(q, 16); q += __shfl_xor(q, 32);
        if ((tid & 48) == 0) {  // one lane per tx per wave
            atomicAdd(&colS[tx * 4 + j], s);
            atomicAdd(&colQ[tx * 4 + j], q);
        }
    }
    __syncthreads();
    if (tid < BN) {
        atomicAdd(&sout[bn + tid], colS[tid]);
        atomicAdd(&qout[bn + tid], colQ[tid]);
    }
}

// ---------------- Dice elementwise + D col stats ----------------
__global__ __launch_bounds__(256) void dice_stats(
    const float* __restrict__ X, float* __restrict__ D,
    const float* __restrict__ sin_, const float* __restrict__ qin_,
    const float* __restrict__ alpha,
    float* __restrict__ sout, float* __restrict__ qout,
    int N, float invB)
{
    __shared__ float cS[64], cQ[64];
    const int t = threadIdx.x;
    const int col = blockIdx.x * 64 + (t & 63);
    const int r0 = blockIdx.y * 64 + (t >> 6);
    if (t < 64) { cS[t] = 0.f; cQ[t] = 0.f; }
    __syncthreads();

    const float m = sin_[col] * invB;
    const float v = fmaf(-m, m, qin_[col] * invB);
    const float rs = rsqrtf(v + 1e-5f);
    const float al = alpha[col];

    float s = 0.f, q = 0.f;
    #pragma unroll
    for (int i = 0; i < 16; ++i) {
        const int r = r0 + i * 4;
        const float x = X[(size_t)r * N + col];
        const float xn = (x - m) * rs;
        const float p = 1.f / (1.f + __expf(-xn));
        const float d = x * (p + al * (1.f - p));
        D[(size_t)r * N + col] = d;
        s += d; q = fmaf(d, d, q);
    }
    atomicAdd(&cS[t & 63], s);
    atomicAdd(&cQ[t & 63], q);
    __syncthreads();
    if (t < 64) {
        atomicAdd(&sout[blockIdx.x * 64 + t], cS[t]);
        atomicAdd(&qout[blockIdx.x * 64 + t], cQ[t]);
    }
}

// ---------------- final: BN-fold + logit, prob, l2 ----------------
__global__ __launch_bounds__(256) void final_k(
    const float* __restrict__ Y, const float* __restrict__ Wout,
    const float* __restrict__ bout, const float* __restrict__ norm_acc,
    const float* __restrict__ sD, const float* __restrict__ qD,
    const float* __restrict__ g, const float* __restrict__ be,
    float invB, float* __restrict__ out)
{
    const int wv = threadIdx.x >> 6, lane = threadIdx.x & 63;
    const int b = blockIdx.x * 4 + wv;
    const float* y = Y + (size_t)b * 128;

    float s = 0.f;
    #pragma unroll
    for (int h = 0; h < 2; ++h) {
        const int c = h * 64 + lane;
        const float m = sD[c] * invB;
        const float v = fmaf(-m, m, qD[c] * invB);
        const float yn = g[c] * (y[c] - m) * rsqrtf(v + 1e-5f) + be[c];
        s = fmaf(yn, Wout[c], s);
    }
    s += __shfl_xor(s, 32); s += __shfl_xor(s, 16);
    s += __shfl_xor(s, 8);  s += __shfl_xor(s, 4);
    s += __shfl_xor(s, 2);  s += __shfl_xor(s, 1);
    if (lane == 0) {
        float logit = s + bout[0];
        out[B_ + b] = logit;
        out[b] = 1.f / (1.f + __expf(-logit));
    }
    if (blockIdx.x == 0 && threadIdx.x == 0)
        out[2 * B_] = 0.2f * norm_acc[0] / (float)B_;
}

extern "C" void kernel_launch(void* const* d_in, const int* in_sizes, int n_in,
                              void* d_out, int out_size, void* d_ws, size_t ws_size,
                              hipStream_t stream)
{
    const float* dense    = (const float*)d_in[0];
    const int*   userid   = (const int*)d_in[1];
    const int*   device_  = (const int*)d_in[2];
    const int*   authorid = (const int*)d_in[3];
    const int*   song     = (const int*)d_in[4];
    const int*   singer   = (const int*)d_in[5];
    const int*   tag      = (const int*)d_in[6];
    const int*   feedid   = (const int*)d_in[7];
    const int*   seq_ids  = (const int*)d_in[8];
    const int*   seq_len  = (const int*)d_in[9];
    const float* e_user   = (const float*)d_in[10];
    const float* e_dev    = (const float*)d_in[11];
    const float* e_auth   = (const float*)d_in[12];
    const float* e_song   = (const float*)d_in[13];
    const float* e_singer = (const float*)d_in[14];
    const float* e_tag    = (const float*)d_in[15];
    const float* e_feed   = (const float*)d_in[16];
    const float* e_seq    = (const float*)d_in[17];
    const float* aW1 = (const float*)d_in[18];
    const float* ab1 = (const float*)d_in[19];
    const float* aW2 = (const float*)d_in[20];
    const float* ab2 = (const float*)d_in[21];
    const float* aW3 = (const float*)d_in[22];
    const float* ab3 = (const float*)d_in[23];
    const float* W0 = (const float*)d_in[24]; const float* b0 = (const float*)d_in[25];
    const float* al0 = (const float*)d_in[26]; const float* g0 = (const float*)d_in[27];
    const float* be0 = (const float*)d_in[28];
    const float* W1 = (const float*)d_in[29]; const float* b1 = (const float*)d_in[30];
    const float* al1 = (const float*)d_in[31]; const float* g1 = (const float*)d_in[32];
    const float* be1 = (const float*)d_in[33];
    const float* W2 = (const float*)d_in[34]; const float* b2 = (const float*)d_in[35];
    const float* al2 = (const float*)d_in[36]; const float* g2 = (const float*)d_in[37];
    const float* be2 = (const float*)d_in[38];
    const float* Wout = (const float*)d_in[39]; const float* bout = (const float*)d_in[40];

    float* ws   = (float*)d_ws;
    float* att  = ws + OFF_ATT;
    float* net  = ws + OFF_NET;
    float* buf1 = ws + OFF_BUF1;
    float* buf2 = ws + OFF_BUF2;
    float* acc  = ws + OFF_ACC;
    float* norm = ws + OFF_NORM;
    float* out  = (float*)d_out;

    float* sX0 = acc + 0*512;  float* qX0 = acc + 1*512;
    float* sD0 = acc + 2*512;  float* qD0 = acc + 3*512;
    float* sX1 = acc + 4*512;  float* qX1 = acc + 5*512;
    float* sD1 = acc + 6*512;  float* qD1 = acc + 7*512;
    float* sX2 = acc + 8*512;  float* qX2 = acc + 9*512;
    float* sD2 = acc + 10*512; float* qD2 = acc + 11*512;

    const float invB = 1.f / (float)B_;

    hipLaunchKernelGGL(init_ws, dim3(1), dim3(256), 0, stream, acc);

    hipLaunchKernelGGL(attn_k, dim3(B_), dim3(256), 0, stream,
                       feedid, seq_ids, seq_len, e_feed, e_seq,
                       aW1, ab1, aW2, ab2, aW3, ab3, att);

    hipLaunchKernelGGL(build_net, dim3(B_/256), dim3(256), 0, stream,
                       dense, userid, device_, authorid, song, singer, tag, feedid,
                       e_user, e_dev, e_auth, e_song, e_singer, e_tag, e_feed,
                       att, net, norm);

    // layer 0: 82 -> 512 (no BN fold), stats of X0
    hipLaunchKernelGGL(gemm_bias_stats, dim3(512/BN, B_/BM), dim3(256), 0, stream,
                       net, W0, b0, buf1, B_, 512, 82,
                       nullptr, nullptr, nullptr, nullptr, sX0, qX0, invB);
    hipLaunchKernelGGL(dice_stats, dim3(512/64, B_/64), dim3(256), 0, stream,
                       buf1, buf2, sX0, qX0, al0, sD0, qD0, 512, invB);

    // layer 1: 512 -> 256, BN(D0) folded into A-load, stats of X1
    hipLaunchKernelGGL(gemm_bias_stats, dim3(256/BN, B_/BM), dim3(256), 0, stream,
                       buf2, W1, b1, buf1, B_, 256, 512,
                       sD0, qD0, g0, be0, sX1, qX1, invB);
    hipLaunchKernelGGL(dice_stats, dim3(256/64, B_/64), dim3(256), 0, stream,
                       buf1, buf2, sX1, qX1, al1, sD1, qD1, 256, invB);

    // layer 2: 256 -> 128, BN(D1) folded, stats of X2
    hipLaunchKernelGGL(gemm_bias_stats, dim3(128/BN, B_/BM), dim3(256), 0, stream,
                       buf2, W2, b2, buf1, B_, 128, 256,
                       sD1, qD1, g1, be1, sX2, qX2, invB);
    hipLaunchKernelGGL(dice_stats, dim3(128/64, B_/64), dim3(256), 0, stream,
                       buf1, buf2, sX2, qX2, al2, sD2, qD2, 128, invB);

    // final: BN(D2) folded + output head
    hipLaunchKernelGGL(final_k, dim3(B_/4), dim3(256), 0, stream,
                       buf2, Wout, bout, norm, sD2, qD2, g2, be2, invB, out);
}

// Round 3
// 471.021 us; speedup vs baseline: 1.4518x; 1.0330x over previous
//
#include <hip/hip_runtime.h>
#include <hip/hip_bf16.h>

#define B_ 8192
#define L_ 200

typedef __attribute__((ext_vector_type(4))) short s4v;
typedef __attribute__((ext_vector_type(8))) short s8v;
typedef __attribute__((ext_vector_type(16))) float f32x16;

__device__ __forceinline__ short f2bf(float f) {
    union { float f; unsigned u; } v; v.f = f;
    unsigned r = (v.u + 0x7fffu + ((v.u >> 16) & 1u)) >> 16;
    return (short)r;
}
__device__ __forceinline__ float bf2f(short s) {
    union { unsigned u; float f; } v; v.u = ((unsigned)(unsigned short)s) << 16;
    return v.f;
}

// ---------------- ws layout (floats) ----------------
#define OFF_ATT   0
#define OFF_NET   (OFF_ATT + B_*16)
#define OFF_BUF1  (OFF_NET + B_*82)
#define OFF_BUF2  (OFF_BUF1 + B_*512)
#define OFF_ACC   (OFF_BUF2 + B_*512)
#define OFF_NORM  (OFF_ACC + 12*512)
#define OFF_PREP  (OFF_NORM + 1)
// prep region: W1B[1024] W1D[1024] W1AC[1024] W2F[1024 floats as 2048 shorts]

__global__ __launch_bounds__(256) void init_ws(float* acc) {
    for (int i = threadIdx.x; i < 12*512 + 1; i += 256) acc[i] = 0.f;
}

// ---------------- one-time weight fragment prep ----------------
__global__ __launch_bounds__(256) void prep_w(
    const float* __restrict__ aW1, const float* __restrict__ aW2, float* __restrict__ wsP)
{
    float* W1B = wsP;
    float* W1D = wsP + 1024;
    float* W1AC = wsP + 2048;
    short* W2F = (short*)(wsP + 3072);
    const int t = threadIdx.x;
    for (int idx = t; idx < 1024; idx += 256) {
        int r = idx & 7, l = (idx >> 3) & 63, mt = idx >> 9;
        int i = ((l >> 5) << 3) + r, j = mt * 32 + (l & 31);
        W1B[idx] = aW1[(16 + i) * 64 + j] - aW1[(32 + i) * 64 + j];
        W1D[idx] = aW1[(48 + i) * 64 + j];
    }
    for (int idx = t; idx < 1024; idx += 256) {
        int i = idx & 15, j = idx >> 4;
        W1AC[idx] = aW1[i * 64 + j] + aW1[(32 + i) * 64 + j];
    }
    for (int idx = t; idx < 2048; idx += 256) {
        int r = idx & 7, l = (idx >> 3) & 63, ks = idx >> 9;
        int j2 = ks * 16 + ((l >> 5) << 3) + r, n2 = l & 31;
        W2F[idx] = f2bf(aW2[j2 * 32 + n2]);
    }
}

// ---------------- MFMA attention (transposed, register-resident) ----------------
// layer1: C1T[j][l] = mfma(A=CkT frag, B=K frag)   (2 j-Mtiles, K=16)
// layer2: C2T[n2][l] = mfma(A=W2T frag, B=h1T frag from regs via shfl_xor(32))
// score:  per-lane 16 FMA + 1 shfl_xor(32)
__global__ __launch_bounds__(256) void attn_k(
    const int* __restrict__ feedid, const int* __restrict__ seq_ids,
    const int* __restrict__ seq_len,
    const float* __restrict__ e_feed, const float* __restrict__ e_seq,
    const float* __restrict__ ab1, const float* __restrict__ ab2,
    const float* __restrict__ ab3, const float* __restrict__ aW3,
    const float* __restrict__ wsP, float* __restrict__ att)
{
    __shared__ short KL[224 * 20];   // K bf16, row stride 20 shorts (40 B: 2-way alias, free)
    __shared__ float qS[16];
    __shared__ float qtS[64];
    __shared__ float w3S[32], ab2S[32];
    __shared__ float wS[224];
    __shared__ float pS[16 * 16];

    const float* W1B = wsP;
    const float* W1D = wsP + 1024;
    const float* W1AC = wsP + 2048;
    const short* W2F = (const short*)(wsP + 3072);

    const int b = blockIdx.x, t = threadIdx.x;

    if (t < 16) qS[t] = e_feed[(size_t)feedid[b] * 16 + t];
    if (t >= 32 && t < 64) w3S[t - 32] = aW3[t - 32];
    if (t >= 64 && t < 96) ab2S[t - 64] = ab2[t - 64];
    __syncthreads();

    // gather K rows (f32 -> bf16)
    for (int idx = t; idx < 800; idx += 256) {
        int row = idx >> 2, p = idx & 3;
        int sid = seq_ids[(size_t)b * L_ + row];
        const float4 f4 = ((const float4*)(e_seq + (size_t)sid * 16))[p];
        s4v v; v[0] = f2bf(f4.x); v[1] = f2bf(f4.y); v[2] = f2bf(f4.z); v[3] = f2bf(f4.w);
        *(s4v*)&KL[row * 20 + p * 4] = v;
    }
    if (t < 96) {
        s4v z = {0, 0, 0, 0};
        *(s4v*)&KL[(200 + (t >> 2)) * 20 + (t & 3) * 4] = z;
    }
    // qterm[j] = ab1[j] + sum_i q[i] * (W1a+W1c)[i][j]
    if (t < 64) {
        float s = ab1[t];
        #pragma unroll
        for (int i = 0; i < 16; ++i) s = fmaf(qS[i], W1AC[t * 16 + i], s);
        qtS[t] = s;
    }
    __syncthreads();

    const int h = (t >> 5) & 1, l31 = t & 31, l63 = t & 63, wv = t >> 6;

    union U8 { s8v s; unsigned u[4]; };

    // A frags for layer 1: CkT[j][i] = W1b[i][j] + q[i]*W1d[i][j]
    U8 a1[2];
    #pragma unroll
    for (int mt = 0; mt < 2; ++mt)
        #pragma unroll
        for (int r = 0; r < 8; ++r) {
            int idx = (mt * 64 + l63) * 8 + r;
            float v = fmaf(qS[h * 8 + r], W1D[idx], W1B[idx]);
            a1[mt].s[r] = f2bf(v);
        }
    // A frags for layer 2 (static)
    s8v w2f[4];
    #pragma unroll
    for (int ks = 0; ks < 4; ++ks)
        w2f[ks] = *(const s8v*)&W2F[(ks * 64 + l63) * 8];

    const float ab3v = ab3[0];
    const int len = seq_len[b];

    for (int m = wv; m < 7; m += 4) {
        const int row = m * 32 + l31;
        // B frag: K[row][k-slice]
        s8v bK;
        {
            s4v lo = *(const s4v*)&KL[row * 20 + h * 8];
            s4v hi = *(const s4v*)&KL[row * 20 + h * 8 + 4];
            bK[0] = lo[0]; bK[1] = lo[1]; bK[2] = lo[2]; bK[3] = lo[3];
            bK[4] = hi[0]; bK[5] = hi[1]; bK[6] = hi[2]; bK[7] = hi[3];
        }

        f32x16 c2;
        #pragma unroll
        for (int i = 0; i < 16; ++i) c2[i] = 0.f;

        #pragma unroll
        for (int mt = 0; mt < 2; ++mt) {
            f32x16 c;
            #pragma unroll
            for (int i = 0; i < 16; ++i) c[i] = 0.f;
            c = __builtin_amdgcn_mfma_f32_32x32x16_bf16(a1[mt].s, bK, c, 0, 0, 0);

            // relu(c + qterm) -> packed bf16x2 (own half + swapped half)
            unsigned pk[8], pks[8];
            #pragma unroll
            for (int i = 0; i < 8; ++i) {
                int r0 = 2 * i, r1 = r0 + 1;
                float v0 = fmaxf(c[r0] + qtS[mt * 32 + (r0 & 3) + 8 * (r0 >> 2) + 4 * h], 0.f);
                float v1 = fmaxf(c[r1] + qtS[mt * 32 + (r1 & 3) + 8 * (r1 >> 2) + 4 * h], 0.f);
                pk[i] = ((unsigned)(unsigned short)f2bf(v1) << 16)
                      | (unsigned)(unsigned short)f2bf(v0);
                pks[i] = __shfl_xor(pk[i], 32);
            }
            // layer 2: two K-steps per mtile
            #pragma unroll
            for (int kss = 0; kss < 2; ++kss) {
                const int ks = mt * 2 + kss;
                const int ib = (kss * 2 + h) * 2;
                U8 bf2;
                bf2.u[0] = h ? pks[ib]     : pk[ib];
                bf2.u[1] = h ? pks[ib + 1] : pk[ib + 1];
                bf2.u[2] = h ? pk[ib]      : pks[ib];
                bf2.u[3] = h ? pk[ib + 1]  : pks[ib + 1];
                c2 = __builtin_amdgcn_mfma_f32_32x32x16_bf16(w2f[ks], bf2.s, c2, 0, 0, 0);
            }
        }

        // score for column l = row
        float part = 0.f;
        #pragma unroll
        for (int r = 0; r < 16; ++r) {
            int n2 = (r & 3) + 8 * (r >> 2) + 4 * h;
            part = fmaf(fmaxf(c2[r] + ab2S[n2], 0.f), w3S[n2], part);
        }
        float tot = part + __shfl_xor(part, 32) + ab3v;
        if (h == 0) wS[row] = (row < len) ? tot : 0.f;
    }
    __syncthreads();

    // att_out[c] = sum_l w[l] * K[l][c]
    {
        const int c = t & 15, ch = t >> 4, r0 = ch * 14;
        float s = 0.f;
        #pragma unroll
        for (int i = 0; i < 14; ++i)
            s = fmaf(wS[r0 + i], bf2f(KL[(r0 + i) * 20 + c]), s);
        pS[ch * 16 + c] = s;
    }
    __syncthreads();
    if (t < 16) {
        float s = 0.f;
        #pragma unroll
        for (int ch = 0; ch < 16; ++ch) s += pS[ch * 16 + t];
        att[(size_t)b * 16 + t] = s;
    }
}

// ---------------- build net matrix + l2 norm ----------------
__global__ __launch_bounds__(256) void build_net(
    const float* __restrict__ dense,
    const int* __restrict__ userid, const int* __restrict__ device_,
    const int* __restrict__ authorid, const int* __restrict__ song,
    const int* __restrict__ singer, const int* __restrict__ tag,
    const int* __restrict__ feedid,
    const float* __restrict__ e_user, const float* __restrict__ e_dev,
    const float* __restrict__ e_auth, const float* __restrict__ e_song,
    const float* __restrict__ e_singer, const float* __restrict__ e_tag,
    const float* __restrict__ e_feed,
    const float* __restrict__ att, float* __restrict__ net,
    float* __restrict__ norm_acc)
{
    const int b = blockIdx.x * 256 + threadIdx.x;
    float row[82];
    const float* d = dense + (size_t)b * 16;
    #pragma unroll
    for (int i = 0; i < 16; ++i) row[i] = d[i];
    const float* eu = e_user + (size_t)userid[b] * 16;
    #pragma unroll
    for (int i = 0; i < 16; ++i) row[16 + i] = eu[i];
    const float* ed = e_dev + (size_t)device_[b] * 2;
    row[32] = ed[0]; row[33] = ed[1];
    const float* ea = e_auth + (size_t)authorid[b] * 4;
    #pragma unroll
    for (int i = 0; i < 4; ++i) row[34 + i] = ea[i];
    const float* es = e_song + (size_t)song[b] * 4;
    #pragma unroll
    for (int i = 0; i < 4; ++i) row[38 + i] = es[i];
    const float* eg = e_singer + (size_t)singer[b] * 4;
    #pragma unroll
    for (int i = 0; i < 4; ++i) row[42 + i] = eg[i];
    const float* et = e_tag + (size_t)tag[b] * 4;
    #pragma unroll
    for (int i = 0; i < 4; ++i) row[46 + i] = et[i];
    const float* ef = e_feed + (size_t)feedid[b] * 16;
    #pragma unroll
    for (int i = 0; i < 16; ++i) row[50 + i] = ef[i];
    const float* at = att + (size_t)b * 16;
    #pragma unroll
    for (int i = 0; i < 16; ++i) row[66 + i] = at[i];

    float sq = 0.f;
    #pragma unroll
    for (int i = 16; i < 82; ++i) sq = fmaf(row[i], row[i], sq);

    float* o = net + (size_t)b * 82;
    #pragma unroll
    for (int i = 0; i < 82; ++i) o[i] = row[i];

    float nrm = sqrtf(sq);
    nrm += __shfl_xor(nrm, 32); nrm += __shfl_xor(nrm, 16);
    nrm += __shfl_xor(nrm, 8);  nrm += __shfl_xor(nrm, 4);
    nrm += __shfl_xor(nrm, 2);  nrm += __shfl_xor(nrm, 1);
    if ((threadIdx.x & 63) == 0) atomicAdd(norm_acc, nrm);
}

// ---------------- f32 GEMM + bias + optional BN-fold on A + output col stats ----------------
#define BM 64
#define BN 64
#define BK 16
__global__ __launch_bounds__(256) void gemm_bias_stats(
    const float* __restrict__ A, const float* __restrict__ Bm,
    const float* __restrict__ bias, float* __restrict__ C,
    int M, int N, int K,
    const float* __restrict__ sin_, const float* __restrict__ qin_,
    const float* __restrict__ gin_, const float* __restrict__ bein_,
    float* __restrict__ sout, float* __restrict__ qout, float invB)
{
    __shared__ float As[BK][BM];
    __shared__ float Bs[BK][BN];
    __shared__ float scl[512], sft[512];
    __shared__ float colS[BN], colQ[BN];

    const int bm = blockIdx.y * BM, bn = blockIdx.x * BN;
    const int tid = threadIdx.x;
    const int tx = tid & 15, ty = tid >> 4;

    if (tid < BN) { colS[tid] = 0.f; colQ[tid] = 0.f; }
    for (int c = tid; c < K; c += 256) {
        if (gin_) {
            float m = sin_[c] * invB;
            float v = fmaf(-m, m, qin_[c] * invB);
            float sc = gin_[c] * rsqrtf(v + 1e-5f);
            scl[c] = sc; sft[c] = bein_[c] - m * sc;
        } else { scl[c] = 1.f; sft[c] = 0.f; }
    }
    __syncthreads();

    float acc[4][4] = {{0.f}};
    for (int k0 = 0; k0 < K; k0 += BK) {
        {
            int m = tid >> 2, kb = (tid & 3) * 4;
            const float* Ap = A + (size_t)(bm + m) * K + k0 + kb;
            #pragma unroll
            for (int j = 0; j < 4; ++j) {
                int kg = k0 + kb + j;
                As[kb + j][m] = (kg < K) ? fmaf(Ap[j], scl[kg], sft[kg]) : 0.f;
            }
        }
        {
            #pragma unroll
            for (int r = 0; r < 4; ++r) {
                int idx = tid + 256 * r;
                int kk = idx >> 6, n = idx & 63;
                int kg = k0 + kk;
                Bs[kk][n] = (kg < K) ? Bm[(size_t)kg * N + bn + n] : 0.f;
            }
        }
        __syncthreads();
        #pragma unroll
        for (int kk = 0; kk < BK; ++kk) {
            float a[4], bb[4];
            #pragma unroll
            for (int i = 0; i < 4; ++i) a[i] = As[kk][ty * 4 + i];
            #pragma unroll
            for (int i = 0; i < 4; ++i) bb[i] = Bs[kk][tx * 4 + i];
            #pragma unroll
            for (int i = 0; i < 4; ++i)
                #pragma unroll
                for (int j = 0; j < 4; ++j)
                    acc[i][j] = fmaf(a[i], bb[j], acc[i][j]);
        }
        __syncthreads();
    }

    #pragma unroll
    for (int j = 0; j < 4; ++j) {
        const int n = bn + tx * 4 + j;
        const float bv = bias[n];
        float s = 0.f, q = 0.f;
        #pragma unroll
        for (int i = 0; i < 4; ++i) {
            float x = acc[i][j] + bv;
            C[(size_t)(bm + ty * 4 + i) * N + n] = x;
            s += x; q = fmaf(x, x, q);
        }
        s += __shfl_xor(s, 16); s += __shfl_xor(s, 32);
        q += __shfl_xor(q, 16); q += __shfl_xor(q, 32);
        if ((tid & 48) == 0) {
            atomicAdd(&colS[tx * 4 + j], s);
            atomicAdd(&colQ[tx * 4 + j], q);
        }
    }
    __syncthreads();
    if (tid < BN) {
        atomicAdd(&sout[bn + tid], colS[tid]);
        atomicAdd(&qout[bn + tid], colQ[tid]);
    }
}

// ---------------- Dice elementwise + D col stats ----------------
__global__ __launch_bounds__(256) void dice_stats(
    const float* __restrict__ X, float* __restrict__ D,
    const float* __restrict__ sin_, const float* __restrict__ qin_,
    const float* __restrict__ alpha,
    float* __restrict__ sout, float* __restrict__ qout,
    int N, float invB)
{
    __shared__ float cS[64], cQ[64];
    const int t = threadIdx.x;
    const int col = blockIdx.x * 64 + (t & 63);
    const int r0 = blockIdx.y * 64 + (t >> 6);
    if (t < 64) { cS[t] = 0.f; cQ[t] = 0.f; }
    __syncthreads();

    const float m = sin_[col] * invB;
    const float v = fmaf(-m, m, qin_[col] * invB);
    const float rs = rsqrtf(v + 1e-5f);
    const float al = alpha[col];

    float s = 0.f, q = 0.f;
    #pragma unroll
    for (int i = 0; i < 16; ++i) {
        const int r = r0 + i * 4;
        const float x = X[(size_t)r * N + col];
        const float xn = (x - m) * rs;
        const float p = 1.f / (1.f + __expf(-xn));
        const float d = x * (p + al * (1.f - p));
        D[(size_t)r * N + col] = d;
        s += d; q = fmaf(d, d, q);
    }
    atomicAdd(&cS[t & 63], s);
    atomicAdd(&cQ[t & 63], q);
    __syncthreads();
    if (t < 64) {
        atomicAdd(&sout[blockIdx.x * 64 + t], cS[t]);
        atomicAdd(&qout[blockIdx.x * 64 + t], cQ[t]);
    }
}

// ---------------- final: BN-fold + logit, prob, l2 ----------------
__global__ __launch_bounds__(256) void final_k(
    const float* __restrict__ Y, const float* __restrict__ Wout,
    const float* __restrict__ bout, const float* __restrict__ norm_acc,
    const float* __restrict__ sD, const float* __restrict__ qD,
    const float* __restrict__ g, const float* __restrict__ be,
    float invB, float* __restrict__ out)
{
    const int wv = threadIdx.x >> 6, lane = threadIdx.x & 63;
    const int b = blockIdx.x * 4 + wv;
    const float* y = Y + (size_t)b * 128;

    float s = 0.f;
    #pragma unroll
    for (int h = 0; h < 2; ++h) {
        const int c = h * 64 + lane;
        const float m = sD[c] * invB;
        const float v = fmaf(-m, m, qD[c] * invB);
        const float yn = g[c] * (y[c] - m) * rsqrtf(v + 1e-5f) + be[c];
        s = fmaf(yn, Wout[c], s);
    }
    s += __shfl_xor(s, 32); s += __shfl_xor(s, 16);
    s += __shfl_xor(s, 8);  s += __shfl_xor(s, 4);
    s += __shfl_xor(s, 2);  s += __shfl_xor(s, 1);
    if (lane == 0) {
        float logit = s + bout[0];
        out[B_ + b] = logit;
        out[b] = 1.f / (1.f + __expf(-logit));
    }
    if (blockIdx.x == 0 && threadIdx.x == 0)
        out[2 * B_] = 0.2f * norm_acc[0] / (float)B_;
}

extern "C" void kernel_launch(void* const* d_in, const int* in_sizes, int n_in,
                              void* d_out, int out_size, void* d_ws, size_t ws_size,
                              hipStream_t stream)
{
    const float* dense    = (const float*)d_in[0];
    const int*   userid   = (const int*)d_in[1];
    const int*   device_  = (const int*)d_in[2];
    const int*   authorid = (const int*)d_in[3];
    const int*   song     = (const int*)d_in[4];
    const int*   singer   = (const int*)d_in[5];
    const int*   tag      = (const int*)d_in[6];
    const int*   feedid   = (const int*)d_in[7];
    const int*   seq_ids  = (const int*)d_in[8];
    const int*   seq_len  = (const int*)d_in[9];
    const float* e_user   = (const float*)d_in[10];
    const float* e_dev    = (const float*)d_in[11];
    const float* e_auth   = (const float*)d_in[12];
    const float* e_song   = (const float*)d_in[13];
    const float* e_singer = (const float*)d_in[14];
    const float* e_tag    = (const float*)d_in[15];
    const float* e_feed   = (const float*)d_in[16];
    const float* e_seq    = (const float*)d_in[17];
    const float* aW1 = (const float*)d_in[18];
    const float* ab1 = (const float*)d_in[19];
    const float* aW2 = (const float*)d_in[20];
    const float* ab2 = (const float*)d_in[21];
    const float* aW3 = (const float*)d_in[22];
    const float* ab3 = (const float*)d_in[23];
    const float* W0 = (const float*)d_in[24]; const float* b0 = (const float*)d_in[25];
    const float* al0 = (const float*)d_in[26]; const float* g0 = (const float*)d_in[27];
    const float* be0 = (const float*)d_in[28];
    const float* W1 = (const float*)d_in[29]; const float* b1 = (const float*)d_in[30];
    const float* al1 = (const float*)d_in[31]; const float* g1 = (const float*)d_in[32];
    const float* be1 = (const float*)d_in[33];
    const float* W2 = (const float*)d_in[34]; const float* b2 = (const float*)d_in[35];
    const float* al2 = (const float*)d_in[36]; const float* g2 = (const float*)d_in[37];
    const float* be2 = (const float*)d_in[38];
    const float* Wout = (const float*)d_in[39]; const float* bout = (const float*)d_in[40];

    float* ws   = (float*)d_ws;
    float* att  = ws + OFF_ATT;
    float* net  = ws + OFF_NET;
    float* buf1 = ws + OFF_BUF1;
    float* buf2 = ws + OFF_BUF2;
    float* acc  = ws + OFF_ACC;
    float* norm = ws + OFF_NORM;
    float* prep = ws + OFF_PREP;
    float* out  = (float*)d_out;

    float* sX0 = acc + 0*512;  float* qX0 = acc + 1*512;
    float* sD0 = acc + 2*512;  float* qD0 = acc + 3*512;
    float* sX1 = acc + 4*512;  float* qX1 = acc + 5*512;
    float* sD1 = acc + 6*512;  float* qD1 = acc + 7*512;
    float* sX2 = acc + 8*512;  float* qX2 = acc + 9*512;
    float* sD2 = acc + 10*512; float* qD2 = acc + 11*512;

    const float invB = 1.f / (float)B_;

    hipLaunchKernelGGL(init_ws, dim3(1), dim3(256), 0, stream, acc);
    hipLaunchKernelGGL(prep_w, dim3(1), dim3(256), 0, stream, aW1, aW2, prep);

    hipLaunchKernelGGL(attn_k, dim3(B_), dim3(256), 0, stream,
                       feedid, seq_ids, seq_len, e_feed, e_seq,
                       ab1, ab2, ab3, aW3, prep, att);

    hipLaunchKernelGGL(build_net, dim3(B_/256), dim3(256), 0, stream,
                       dense, userid, device_, authorid, song, singer, tag, feedid,
                       e_user, e_dev, e_auth, e_song, e_singer, e_tag, e_feed,
                       att, net, norm);

    // layer 0: 82 -> 512 (no BN fold), stats of X0
    hipLaunchKernelGGL(gemm_bias_stats, dim3(512/BN, B_/BM), dim3(256), 0, stream,
                       net, W0, b0, buf1, B_, 512, 82,
                       nullptr, nullptr, nullptr, nullptr, sX0, qX0, invB);
    hipLaunchKernelGGL(dice_stats, dim3(512/64, B_/64), dim3(256), 0, stream,
                       buf1, buf2, sX0, qX0, al0, sD0, qD0, 512, invB);

    // layer 1: 512 -> 256, BN(D0) folded into A-load, stats of X1
    hipLaunchKernelGGL(gemm_bias_stats, dim3(256/BN, B_/BM), dim3(256), 0, stream,
                       buf2, W1, b1, buf1, B_, 256, 512,
                       sD0, qD0, g0, be0, sX1, qX1, invB);
    hipLaunchKernelGGL(dice_stats, dim3(256/64, B_/64), dim3(256), 0, stream,
                       buf1, buf2, sX1, qX1, al1, sD1, qD1, 256, invB);

    // layer 2: 256 -> 128, BN(D1) folded, stats of X2
    hipLaunchKernelGGL(gemm_bias_stats, dim3(128/BN, B_/BM), dim3(256), 0, stream,
                       buf2, W2, b2, buf1, B_, 128, 256,
                       sD1, qD1, g1, be1, sX2, qX2, invB);
    hipLaunchKernelGGL(dice_stats, dim3(128/64, B_/64), dim3(256), 0, stream,
                       buf1, buf2, sX2, qX2, al2, sD2, qD2, 128, invB);

    // final: BN(D2) folded + output head
    hipLaunchKernelGGL(final_k, dim3(B_/4), dim3(256), 0, stream,
                       buf2, Wout, bout, norm, sD2, qD2, g2, be2, invB, out);
}

// Round 4
// 412.302 us; speedup vs baseline: 1.6586x; 1.1424x over previous
//
#include <hip/hip_runtime.h>
#include <hip/hip_bf16.h>

#define B_ 8192
#define L_ 200

typedef __attribute__((ext_vector_type(4))) short s4v;
typedef __attribute__((ext_vector_type(8))) short s8v;
typedef __attribute__((ext_vector_type(16))) float f32x16;

__device__ __forceinline__ short f2bf(float f) {
    union { float f; unsigned u; } v; v.f = f;
    unsigned r = (v.u + 0x7fffu + ((v.u >> 16) & 1u)) >> 16;
    return (short)r;
}
__device__ __forceinline__ float bf2f(short s) {
    union { unsigned u; float f; } v; v.u = ((unsigned)(unsigned short)s) << 16;
    return v.f;
}

// ---------------- ws layout (floats) ----------------
#define OFF_ATT   0
#define OFF_NET   (OFF_ATT + B_*16)
#define OFF_BUF1  (OFF_NET + B_*82)
#define OFF_BUF2  (OFF_BUF1 + B_*512)
#define OFF_ACC   (OFF_BUF2 + B_*512)
#define OFF_NORM  (OFF_ACC + 12*512)
#define OFF_PREP  (OFF_NORM + 1)

__global__ __launch_bounds__(256) void init_ws(float* acc) {
    for (int i = threadIdx.x; i < 12*512 + 1; i += 256) acc[i] = 0.f;
}

// ---------------- one-time weight fragment prep ----------------
__global__ __launch_bounds__(256) void prep_w(
    const float* __restrict__ aW1, const float* __restrict__ aW2, float* __restrict__ wsP)
{
    float* W1B = wsP;
    float* W1D = wsP + 1024;
    float* W1AC = wsP + 2048;
    short* W2F = (short*)(wsP + 3072);
    const int t = threadIdx.x;
    for (int idx = t; idx < 1024; idx += 256) {
        int r = idx & 7, l = (idx >> 3) & 63, mt = idx >> 9;
        int i = ((l >> 5) << 3) + r, j = mt * 32 + (l & 31);
        W1B[idx] = aW1[(16 + i) * 64 + j] - aW1[(32 + i) * 64 + j];
        W1D[idx] = aW1[(48 + i) * 64 + j];
    }
    for (int idx = t; idx < 1024; idx += 256) {
        int i = idx & 15, j = idx >> 4;
        W1AC[idx] = aW1[i * 64 + j] + aW1[(32 + i) * 64 + j];
    }
    for (int idx = t; idx < 2048; idx += 256) {
        int r = idx & 7, l = (idx >> 3) & 63, ks = idx >> 9;
        int j2 = ks * 16 + ((l >> 5) << 3) + r, n2 = l & 31;
        W2F[idx] = f2bf(aW2[j2 * 32 + n2]);
    }
}

// ---------------- MFMA attention (transposed, register-resident) ----------------
__global__ __launch_bounds__(256) void attn_k(
    const int* __restrict__ feedid, const int* __restrict__ seq_ids,
    const int* __restrict__ seq_len,
    const float* __restrict__ e_feed, const float* __restrict__ e_seq,
    const float* __restrict__ ab1, const float* __restrict__ ab2,
    const float* __restrict__ ab3, const float* __restrict__ aW3,
    const float* __restrict__ wsP, float* __restrict__ att)
{
    __shared__ short KL[224 * 20];   // K bf16, row stride 20 shorts (40 B: 2-way alias, free)
    __shared__ float qS[16];
    __shared__ float qtS[64];
    __shared__ float w3S[32], ab2S[32];
    __shared__ float wS[224];
    __shared__ float pS[16 * 16];

    const float* W1B = wsP;
    const float* W1D = wsP + 1024;
    const float* W1AC = wsP + 2048;
    const short* W2F = (const short*)(wsP + 3072);

    const int b = blockIdx.x, t = threadIdx.x;

    if (t < 16) qS[t] = e_feed[(size_t)feedid[b] * 16 + t];
    if (t >= 32 && t < 64) w3S[t - 32] = aW3[t - 32];
    if (t >= 64 && t < 96) ab2S[t - 64] = ab2[t - 64];
    __syncthreads();

    // gather K rows (f32 -> bf16)
    for (int idx = t; idx < 800; idx += 256) {
        int row = idx >> 2, p = idx & 3;
        int sid = seq_ids[(size_t)b * L_ + row];
        const float4 f4 = ((const float4*)(e_seq + (size_t)sid * 16))[p];
        s4v v; v[0] = f2bf(f4.x); v[1] = f2bf(f4.y); v[2] = f2bf(f4.z); v[3] = f2bf(f4.w);
        *(s4v*)&KL[row * 20 + p * 4] = v;
    }
    if (t < 96) {
        s4v z = {0, 0, 0, 0};
        *(s4v*)&KL[(200 + (t >> 2)) * 20 + (t & 3) * 4] = z;
    }
    if (t < 64) {
        float s = ab1[t];
        #pragma unroll
        for (int i = 0; i < 16; ++i) s = fmaf(qS[i], W1AC[t * 16 + i], s);
        qtS[t] = s;
    }
    __syncthreads();

    const int h = (t >> 5) & 1, l31 = t & 31, l63 = t & 63, wv = t >> 6;

    union U8 { s8v s; unsigned u[4]; };

    // A frags for layer 1: CkT[j][i] = W1b[i][j] + q[i]*W1d[i][j]
    U8 a1[2];
    #pragma unroll
    for (int mt = 0; mt < 2; ++mt)
        #pragma unroll
        for (int r = 0; r < 8; ++r) {
            int idx = (mt * 64 + l63) * 8 + r;
            float v = fmaf(qS[h * 8 + r], W1D[idx], W1B[idx]);
            a1[mt].s[r] = f2bf(v);
        }
    s8v w2f[4];
    #pragma unroll
    for (int ks = 0; ks < 4; ++ks)
        w2f[ks] = *(const s8v*)&W2F[(ks * 64 + l63) * 8];

    const float ab3v = ab3[0];
    const int len = seq_len[b];

    for (int m = wv; m < 7; m += 4) {
        const int row = m * 32 + l31;
        s8v bK;
        {
            s4v lo = *(const s4v*)&KL[row * 20 + h * 8];
            s4v hi = *(const s4v*)&KL[row * 20 + h * 8 + 4];
            bK[0] = lo[0]; bK[1] = lo[1]; bK[2] = lo[2]; bK[3] = lo[3];
            bK[4] = hi[0]; bK[5] = hi[1]; bK[6] = hi[2]; bK[7] = hi[3];
        }

        f32x16 c2;
        #pragma unroll
        for (int i = 0; i < 16; ++i) c2[i] = 0.f;

        #pragma unroll
        for (int mt = 0; mt < 2; ++mt) {
            f32x16 c;
            #pragma unroll
            for (int i = 0; i < 16; ++i) c[i] = 0.f;
            c = __builtin_amdgcn_mfma_f32_32x32x16_bf16(a1[mt].s, bK, c, 0, 0, 0);

            // relu(c + qterm) -> packed bf16x2 (own half + swapped half); ALL indices static
            unsigned pk[8], pks[8];
            #pragma unroll
            for (int i = 0; i < 8; ++i) {
                int r0 = 2 * i, r1 = r0 + 1;
                float v0 = fmaxf(c[r0] + qtS[mt * 32 + (r0 & 3) + 8 * (r0 >> 2) + 4 * h], 0.f);
                float v1 = fmaxf(c[r1] + qtS[mt * 32 + (r1 & 3) + 8 * (r1 >> 2) + 4 * h], 0.f);
                pk[i] = ((unsigned)(unsigned short)f2bf(v1) << 16)
                      | (unsigned)(unsigned short)f2bf(v0);
                pks[i] = __shfl_xor(pk[i], 32);
            }
            // layer 2 K-step A (static indices, h-select via cndmask)
            {
                U8 bf2;
                bf2.u[0] = h ? pks[2] : pk[0];
                bf2.u[1] = h ? pks[3] : pk[1];
                bf2.u[2] = h ? pk[2]  : pks[0];
                bf2.u[3] = h ? pk[3]  : pks[1];
                c2 = __builtin_amdgcn_mfma_f32_32x32x16_bf16(w2f[mt * 2], bf2.s, c2, 0, 0, 0);
            }
            {
                U8 bf2;
                bf2.u[0] = h ? pks[6] : pk[4];
                bf2.u[1] = h ? pks[7] : pk[5];
                bf2.u[2] = h ? pk[6]  : pks[4];
                bf2.u[3] = h ? pk[7]  : pks[5];
                c2 = __builtin_amdgcn_mfma_f32_32x32x16_bf16(w2f[mt * 2 + 1], bf2.s, c2, 0, 0, 0);
            }
        }

        float part = 0.f;
        #pragma unroll
        for (int r = 0; r < 16; ++r) {
            int n2 = (r & 3) + 8 * (r >> 2) + 4 * h;
            part = fmaf(fmaxf(c2[r] + ab2S[n2], 0.f), w3S[n2], part);
        }
        float tot = part + __shfl_xor(part, 32) + ab3v;
        if (h == 0) wS[row] = (row < len) ? tot : 0.f;
    }
    __syncthreads();

    {
        const int c = t & 15, ch = t >> 4, r0 = ch * 14;
        float s = 0.f;
        #pragma unroll
        for (int i = 0; i < 14; ++i)
            s = fmaf(wS[r0 + i], bf2f(KL[(r0 + i) * 20 + c]), s);
        pS[ch * 16 + c] = s;
    }
    __syncthreads();
    if (t < 16) {
        float s = 0.f;
        #pragma unroll
        for (int ch = 0; ch < 16; ++ch) s += pS[ch * 16 + t];
        att[(size_t)b * 16 + t] = s;
    }
}

// ---------------- build net matrix + l2 norm ----------------
__global__ __launch_bounds__(256) void build_net(
    const float* __restrict__ dense,
    const int* __restrict__ userid, const int* __restrict__ device_,
    const int* __restrict__ authorid, const int* __restrict__ song,
    const int* __restrict__ singer, const int* __restrict__ tag,
    const int* __restrict__ feedid,
    const float* __restrict__ e_user, const float* __restrict__ e_dev,
    const float* __restrict__ e_auth, const float* __restrict__ e_song,
    const float* __restrict__ e_singer, const float* __restrict__ e_tag,
    const float* __restrict__ e_feed,
    const float* __restrict__ att, float* __restrict__ net,
    float* __restrict__ norm_acc)
{
    const int b = blockIdx.x * 256 + threadIdx.x;
    float row[82];
    const float* d = dense + (size_t)b * 16;
    #pragma unroll
    for (int i = 0; i < 16; ++i) row[i] = d[i];
    const float* eu = e_user + (size_t)userid[b] * 16;
    #pragma unroll
    for (int i = 0; i < 16; ++i) row[16 + i] = eu[i];
    const float* ed = e_dev + (size_t)device_[b] * 2;
    row[32] = ed[0]; row[33] = ed[1];
    const float* ea = e_auth + (size_t)authorid[b] * 4;
    #pragma unroll
    for (int i = 0; i < 4; ++i) row[34 + i] = ea[i];
    const float* es = e_song + (size_t)song[b] * 4;
    #pragma unroll
    for (int i = 0; i < 4; ++i) row[38 + i] = es[i];
    const float* eg = e_singer + (size_t)singer[b] * 4;
    #pragma unroll
    for (int i = 0; i < 4; ++i) row[42 + i] = eg[i];
    const float* et = e_tag + (size_t)tag[b] * 4;
    #pragma unroll
    for (int i = 0; i < 4; ++i) row[46 + i] = et[i];
    const float* ef = e_feed + (size_t)feedid[b] * 16;
    #pragma unroll
    for (int i = 0; i < 16; ++i) row[50 + i] = ef[i];
    const float* at = att + (size_t)b * 16;
    #pragma unroll
    for (int i = 0; i < 16; ++i) row[66 + i] = at[i];

    float sq = 0.f;
    #pragma unroll
    for (int i = 16; i < 82; ++i) sq = fmaf(row[i], row[i], sq);

    float* o = net + (size_t)b * 82;
    #pragma unroll
    for (int i = 0; i < 82; ++i) o[i] = row[i];

    float nrm = sqrtf(sq);
    nrm += __shfl_xor(nrm, 32); nrm += __shfl_xor(nrm, 16);
    nrm += __shfl_xor(nrm, 8);  nrm += __shfl_xor(nrm, 4);
    nrm += __shfl_xor(nrm, 2);  nrm += __shfl_xor(nrm, 1);
    if ((threadIdx.x & 63) == 0) atomicAdd(norm_acc, nrm);
}

// ---------------- MFMA bf16 GEMM + bias + BN-fold on A + output col stats ----------------
// C[M,N] = (A*scl+sft)[M,K] @ B[K,N] + bias ; 64x64 tile, 4 waves = 2x2 quadrants of 32x32.
__global__ __launch_bounds__(256) void gemm_mfma_stats(
    const float* __restrict__ A, const float* __restrict__ Bm,
    const float* __restrict__ bias, float* __restrict__ C,
    int M, int N, int K,
    const float* __restrict__ sin_, const float* __restrict__ qin_,
    const float* __restrict__ gin_, const float* __restrict__ bein_,
    float* __restrict__ sout, float* __restrict__ qout, float invB)
{
    __shared__ short As[64 * 20];    // [m][k] bf16, stride 20 shorts
    __shared__ short BsT[64 * 20];   // [n][k] bf16, stride 20 shorts
    __shared__ float scl[512], sft[512];
    __shared__ float colS[64], colQ[64];

    const int bm = blockIdx.y * 64, bn = blockIdx.x * 64;
    const int t = threadIdx.x;

    if (t < 64) { colS[t] = 0.f; colQ[t] = 0.f; }
    for (int c = t; c < K; c += 256) {
        if (gin_) {
            float m = sin_[c] * invB;
            float v = fmaf(-m, m, qin_[c] * invB);
            float sc = gin_[c] * rsqrtf(v + 1e-5f);
            scl[c] = sc; sft[c] = bein_[c] - m * sc;
        } else { scl[c] = 1.f; sft[c] = 0.f; }
    }
    __syncthreads();

    const int wv = t >> 6, l31 = t & 31, h = (t >> 5) & 1;
    const int qr = wv >> 1, qc = wv & 1;

    f32x16 acc;
    #pragma unroll
    for (int i = 0; i < 16; ++i) acc[i] = 0.f;

    const int am = t >> 2, akb = (t & 3) * 4;     // A staging: row, k-base
    const int bn_l = t & 63, bk0 = (t >> 6) * 4;  // B staging: col, k-base

    for (int k0 = 0; k0 < K; k0 += 16) {
        {   // stage A (f32 -> BN-fold -> bf16), 8B write per thread
            const float* Ap = A + (size_t)(bm + am) * K + k0 + akb;
            s4v v;
            #pragma unroll
            for (int j = 0; j < 4; ++j) {
                int kg = k0 + akb + j;
                float x = (kg < K) ? fmaf(Ap[j], scl[kg], sft[kg]) : 0.f;
                v[j] = f2bf(x);
            }
            *(s4v*)&As[am * 20 + akb] = v;
        }
        {   // stage B transposed (coalesced read, 2B scattered LDS writes)
            #pragma unroll
            for (int r = 0; r < 4; ++r) {
                int kk = bk0 + r, kg = k0 + kk;
                float x = (kg < K) ? Bm[(size_t)kg * N + bn + bn_l] : 0.f;
                BsT[bn_l * 20 + kk] = f2bf(x);
            }
        }
        __syncthreads();
        const s8v af = *(const s8v*)&As[(qr * 32 + l31) * 20 + h * 8];
        const s8v bf = *(const s8v*)&BsT[(qc * 32 + l31) * 20 + h * 8];
        acc = __builtin_amdgcn_mfma_f32_32x32x16_bf16(af, bf, acc, 0, 0, 0);
        __syncthreads();
    }

    // epilogue: bias, store f32, column stats
    const int col = bn + qc * 32 + l31;
    const float bv = bias[col];
    float s = 0.f, q = 0.f;
    #pragma unroll
    for (int r = 0; r < 16; ++r) {
        const int row = bm + qr * 32 + (r & 3) + 8 * (r >> 2) + 4 * h;
        float x = acc[r] + bv;
        C[(size_t)row * N + col] = x;
        s += x; q = fmaf(x, x, q);
    }
    s += __shfl_xor(s, 32);
    q += __shfl_xor(q, 32);
    if (h == 0) {
        atomicAdd(&colS[qc * 32 + l31], s);
        atomicAdd(&colQ[qc * 32 + l31], q);
    }
    __syncthreads();
    if (t < 64) {
        atomicAdd(&sout[bn + t], colS[t]);
        atomicAdd(&qout[bn + t], colQ[t]);
    }
}

// ---------------- Dice elementwise + D col stats ----------------
__global__ __launch_bounds__(256) void dice_stats(
    const float* __restrict__ X, float* __restrict__ D,
    const float* __restrict__ sin_, const float* __restrict__ qin_,
    const float* __restrict__ alpha,
    float* __restrict__ sout, float* __restrict__ qout,
    int N, float invB)
{
    __shared__ float cS[64], cQ[64];
    const int t = threadIdx.x;
    const int col = blockIdx.x * 64 + (t & 63);
    const int r0 = blockIdx.y * 64 + (t >> 6);
    if (t < 64) { cS[t] = 0.f; cQ[t] = 0.f; }
    __syncthreads();

    const float m = sin_[col] * invB;
    const float v = fmaf(-m, m, qin_[col] * invB);
    const float rs = rsqrtf(v + 1e-5f);
    const float al = alpha[col];

    float s = 0.f, q = 0.f;
    #pragma unroll
    for (int i = 0; i < 16; ++i) {
        const int r = r0 + i * 4;
        const float x = X[(size_t)r * N + col];
        const float xn = (x - m) * rs;
        const float p = 1.f / (1.f + __expf(-xn));
        const float d = x * (p + al * (1.f - p));
        D[(size_t)r * N + col] = d;
        s += d; q = fmaf(d, d, q);
    }
    atomicAdd(&cS[t & 63], s);
    atomicAdd(&cQ[t & 63], q);
    __syncthreads();
    if (t < 64) {
        atomicAdd(&sout[blockIdx.x * 64 + t], cS[t]);
        atomicAdd(&qout[blockIdx.x * 64 + t], cQ[t]);
    }
}

// ---------------- final: BN-fold + logit, prob, l2 ----------------
__global__ __launch_bounds__(256) void final_k(
    const float* __restrict__ Y, const float* __restrict__ Wout,
    const float* __restrict__ bout, const float* __restrict__ norm_acc,
    const float* __restrict__ sD, const float* __restrict__ qD,
    const float* __restrict__ g, const float* __restrict__ be,
    float invB, float* __restrict__ out)
{
    const int wv = threadIdx.x >> 6, lane = threadIdx.x & 63;
    const int b = blockIdx.x * 4 + wv;
    const float* y = Y + (size_t)b * 128;

    float s = 0.f;
    #pragma unroll
    for (int h = 0; h < 2; ++h) {
        const int c = h * 64 + lane;
        const float m = sD[c] * invB;
        const float v = fmaf(-m, m, qD[c] * invB);
        const float yn = g[c] * (y[c] - m) * rsqrtf(v + 1e-5f) + be[c];
        s = fmaf(yn, Wout[c], s);
    }
    s += __shfl_xor(s, 32); s += __shfl_xor(s, 16);
    s += __shfl_xor(s, 8);  s += __shfl_xor(s, 4);
    s += __shfl_xor(s, 2);  s += __shfl_xor(s, 1);
    if (lane == 0) {
        float logit = s + bout[0];
        out[B_ + b] = logit;
        out[b] = 1.f / (1.f + __expf(-logit));
    }
    if (blockIdx.x == 0 && threadIdx.x == 0)
        out[2 * B_] = 0.2f * norm_acc[0] / (float)B_;
}

extern "C" void kernel_launch(void* const* d_in, const int* in_sizes, int n_in,
                              void* d_out, int out_size, void* d_ws, size_t ws_size,
                              hipStream_t stream)
{
    const float* dense    = (const float*)d_in[0];
    const int*   userid   = (const int*)d_in[1];
    const int*   device_  = (const int*)d_in[2];
    const int*   authorid = (const int*)d_in[3];
    const int*   song     = (const int*)d_in[4];
    const int*   singer   = (const int*)d_in[5];
    const int*   tag      = (const int*)d_in[6];
    const int*   feedid   = (const int*)d_in[7];
    const int*   seq_ids  = (const int*)d_in[8];
    const int*   seq_len  = (const int*)d_in[9];
    const float* e_user   = (const float*)d_in[10];
    const float* e_dev    = (const float*)d_in[11];
    const float* e_auth   = (const float*)d_in[12];
    const float* e_song   = (const float*)d_in[13];
    const float* e_singer = (const float*)d_in[14];
    const float* e_tag    = (const float*)d_in[15];
    const float* e_feed   = (const float*)d_in[16];
    const float* e_seq    = (const float*)d_in[17];
    const float* aW1 = (const float*)d_in[18];
    const float* ab1 = (const float*)d_in[19];
    const float* aW2 = (const float*)d_in[20];
    const float* ab2 = (const float*)d_in[21];
    const float* aW3 = (const float*)d_in[22];
    const float* ab3 = (const float*)d_in[23];
    const float* W0 = (const float*)d_in[24]; const float* b0 = (const float*)d_in[25];
    const float* al0 = (const float*)d_in[26]; const float* g0 = (const float*)d_in[27];
    const float* be0 = (const float*)d_in[28];
    const float* W1 = (const float*)d_in[29]; const float* b1 = (const float*)d_in[30];
    const float* al1 = (const float*)d_in[31]; const float* g1 = (const float*)d_in[32];
    const float* be1 = (const float*)d_in[33];
    const float* W2 = (const float*)d_in[34]; const float* b2 = (const float*)d_in[35];
    const float* al2 = (const float*)d_in[36]; const float* g2 = (const float*)d_in[37];
    const float* be2 = (const float*)d_in[38];
    const float* Wout = (const float*)d_in[39]; const float* bout = (const float*)d_in[40];

    float* ws   = (float*)d_ws;
    float* att  = ws + OFF_ATT;
    float* net  = ws + OFF_NET;
    float* buf1 = ws + OFF_BUF1;
    float* buf2 = ws + OFF_BUF2;
    float* acc  = ws + OFF_ACC;
    float* norm = ws + OFF_NORM;
    float* prep = ws + OFF_PREP;
    float* out  = (float*)d_out;

    float* sX0 = acc + 0*512;  float* qX0 = acc + 1*512;
    float* sD0 = acc + 2*512;  float* qD0 = acc + 3*512;
    float* sX1 = acc + 4*512;  float* qX1 = acc + 5*512;
    float* sD1 = acc + 6*512;  float* qD1 = acc + 7*512;
    float* sX2 = acc + 8*512;  float* qX2 = acc + 9*512;
    float* sD2 = acc + 10*512; float* qD2 = acc + 11*512;

    const float invB = 1.f / (float)B_;

    hipLaunchKernelGGL(init_ws, dim3(1), dim3(256), 0, stream, acc);
    hipLaunchKernelGGL(prep_w, dim3(1), dim3(256), 0, stream, aW1, aW2, prep);

    hipLaunchKernelGGL(attn_k, dim3(B_), dim3(256), 0, stream,
                       feedid, seq_ids, seq_len, e_feed, e_seq,
                       ab1, ab2, ab3, aW3, prep, att);

    hipLaunchKernelGGL(build_net, dim3(B_/256), dim3(256), 0, stream,
                       dense, userid, device_, authorid, song, singer, tag, feedid,
                       e_user, e_dev, e_auth, e_song, e_singer, e_tag, e_feed,
                       att, net, norm);

    // layer 0: 82 -> 512 (no BN fold), stats of X0
    hipLaunchKernelGGL(gemm_mfma_stats, dim3(512/64, B_/64), dim3(256), 0, stream,
                       net, W0, b0, buf1, B_, 512, 82,
                       nullptr, nullptr, nullptr, nullptr, sX0, qX0, invB);
    hipLaunchKernelGGL(dice_stats, dim3(512/64, B_/64), dim3(256), 0, stream,
                       buf1, buf2, sX0, qX0, al0, sD0, qD0, 512, invB);

    // layer 1: 512 -> 256, BN(D0) folded into A-load, stats of X1
    hipLaunchKernelGGL(gemm_mfma_stats, dim3(256/64, B_/64), dim3(256), 0, stream,
                       buf2, W1, b1, buf1, B_, 256, 512,
                       sD0, qD0, g0, be0, sX1, qX1, invB);
    hipLaunchKernelGGL(dice_stats, dim3(256/64, B_/64), dim3(256), 0, stream,
                       buf1, buf2, sX1, qX1, al1, sD1, qD1, 256, invB);

    // layer 2: 256 -> 128, BN(D1) folded, stats of X2
    hipLaunchKernelGGL(gemm_mfma_stats, dim3(128/64, B_/64), dim3(256), 0, stream,
                       buf2, W2, b2, buf1, B_, 128, 256,
                       sD1, qD1, g1, be1, sX2, qX2, invB);
    hipLaunchKernelGGL(dice_stats, dim3(128/64, B_/64), dim3(256), 0, stream,
                       buf1, buf2, sX2, qX2, al2, sD2, qD2, 128, invB);

    // final: BN(D2) folded + output head
    hipLaunchKernelGGL(final_k, dim3(B_/4), dim3(256), 0, stream,
                       buf2, Wout, bout, norm, sD2, qD2, g2, be2, invB, out);
}